// Round 14
// baseline (748.259 us; speedup 1.0000x reference)
//
#include <hip/hip_runtime.h>
#include <hip/hip_bf16.h>
#include <hip/hip_fp16.h>
#include <stdint.h>

#define T_STEPS 256
#define BATCH 512

typedef _Float16 f16x8 __attribute__((ext_vector_type(8)));
typedef _Float16 h2_t  __attribute__((ext_vector_type(2)));
typedef float    f32x4 __attribute__((ext_vector_type(4)));

__device__ __forceinline__ float fdot2(uint32_t w, uint32_t c, float acc) {
#if __has_builtin(__builtin_amdgcn_fdot2)
    h2_t a, b;
    __builtin_memcpy(&a, &w, 4);
    __builtin_memcpy(&b, &c, 4);
    return __builtin_amdgcn_fdot2(a, b, acc, false);
#else
    union { uint32_t u; _Float16 h[2]; } A, B;
    A.u = w; B.u = c;
    return acc + (float)A.h[0]*(float)B.h[0] + (float)A.h[1]*(float)B.h[1];
#endif
}

__device__ __forceinline__ float sigmoidf_(float x) {
    return 1.f / (1.f + __expf(-x));
}
__device__ __forceinline__ float tanhf_(float x) {
    float ax = fabsf(x);
    float e = __expf(-2.f * ax);
    float r = (1.f - e) / (1.f + e);
    return copysignf(r, x);
}

// pick-of-4 by d (0..3) without runtime array indexing (3 cndmask)
__device__ __forceinline__ float sel4(int d, float a, float b, float c, float e) {
    float lo = (d & 1) ? b : a;
    float hi = (d & 1) ? e : c;
    return (d & 2) ? hi : lo;
}

// resident-B MFMA, accumulate: D=C=c (tied), B in AGPR
#define MFMA_AG(c, aa, bb) \
    asm volatile("v_mfma_f32_16x16x32_f16 %0, %1, %2, %0" : "+v"(c) : "v"(aa), "a"(bb))
// resident-B MFMA, chain start: D=c fresh, C=zz (shared zero) — kills the
// 64 v_mov/step zero-init AND the VALU->asm-MFMA SrcC hazard window
#define MFMA_AG0(c, aa, bb, zz) \
    asm volatile("v_mfma_f32_16x16x32_f16 %0, %1, %2, %3" : "=&v"(c) : "v"(aa), "a"(bb), "v"(zz))

// ---------------- prep: concat QCNN weights ----------------
__global__ void concat_qw(const float* __restrict__ fm_w, const float* __restrict__ fm_b,
                          const float* __restrict__ c1_w, const float* __restrict__ c1_b,
                          const float* __restrict__ p1_w, const float* __restrict__ p1_b,
                          const float* __restrict__ c2_w, const float* __restrict__ c2_b,
                          const float* __restrict__ p2_w, const float* __restrict__ p2_b,
                          const float* __restrict__ c3_w, const float* __restrict__ c3_b,
                          float* __restrict__ qw) {
    for (int k = threadIdx.x; k < 780; k += 256) {
        float v;
        if      (k < 128) v = fm_w[k];
        else if (k < 144) v = fm_b[k-128];
        else if (k < 400) v = c1_w[k-144];
        else if (k < 416) v = c1_b[k-400];
        else if (k < 608) v = p1_w[k-416];
        else if (k < 620) v = p1_b[k-608];
        else if (k < 716) v = c2_w[k-620];
        else if (k < 724) v = c2_b[k-716];
        else if (k < 756) v = p2_w[k-724];
        else if (k < 760) v = p2_b[k-756];
        else if (k < 776) v = c3_w[k-760];
        else              v = c3_b[k-776];
        qw[k] = v;
    }
}

// ---------------- prep: B-fragments (f16) ----------------
// bfragsG[((n*8+q)*64+l)]: N-tile n (col = n*16 + (l&15) = gate*256 + j),
// K-tile q (k = q*32 + (l>>4)*8 + e). k-order errors cancel (A same mapping).
__global__ void pack_bfrag(const float* __restrict__ f_w, const float* __restrict__ i_w,
                           const float* __restrict__ u_w, const float* __restrict__ o_w,
                           uint4* __restrict__ bfragsG) {
    int idx = blockIdx.x * 256 + threadIdx.x;      // 0..32767
    int l = idx & 63, q = (idx >> 6) & 7, n = idx >> 9;
    int col = n * 16 + (l & 15);
    int g = col >> 8, j = col & 255;
    const float* W = (g == 0) ? f_w : (g == 1) ? i_w : (g == 2) ? u_w : o_w;
    union { uint4 u; _Float16 h[8]; } P;
#pragma unroll
    for (int e = 0; e < 8; ++e) {
        int k = q * 32 + ((l >> 4) * 8) + e;       // 0..255 (h part only)
        P.h[e] = (_Float16)W[j * 260 + 4 + k];
    }
    bfragsG[idx] = P.u;
}

// ---------------- prep: x-part weights xwG[g][k][j] f16 ----------------
__global__ void pack_xw(const float* __restrict__ f_w, const float* __restrict__ i_w,
                        const float* __restrict__ u_w, const float* __restrict__ o_w,
                        _Float16* __restrict__ xwG) {
    int t = blockIdx.x * 256 + threadIdx.x;        // 0..4095
    int g = t >> 10, k = (t >> 8) & 3, j = t & 255;
    const float* W = (g == 0) ? f_w : (g == 1) ? i_w : (g == 2) ? u_w : o_w;
    xwG[t] = (_Float16)W[j * 260 + k];
}

// ---------------- QCNN feature extractor ----------------
__global__ void qcnn_kernel(const float* __restrict__ in, const float* __restrict__ qw,
                            _Float16* __restrict__ feats) {
    int r = blockIdx.x * 256 + threadIdx.x;   // 0..131071
    const float* x = in + (size_t)r * 8;
    float v0[8];
#pragma unroll
    for (int i = 0; i < 8; ++i) v0[i] = x[i];
    float v1[16];
#pragma unroll
    for (int o = 0; o < 16; ++o) {
        float s = qw[128 + o];
#pragma unroll
        for (int i = 0; i < 8; ++i) s += qw[o*8 + i] * v0[i];
        v1[o] = tanhf_(s);
    }
    float v2[16];
#pragma unroll
    for (int o = 0; o < 16; ++o) {
        float s = qw[400 + o];
#pragma unroll
        for (int i = 0; i < 16; ++i) s += qw[144 + o*16 + i] * v1[i];
        v2[o] = tanhf_(s);
    }
    float v3[12];
#pragma unroll
    for (int o = 0; o < 12; ++o) {
        float s = qw[608 + o];
#pragma unroll
        for (int i = 0; i < 16; ++i) s += qw[416 + o*16 + i] * v2[i];
        v3[o] = tanhf_(s);
    }
    float v4[8];
#pragma unroll
    for (int o = 0; o < 8; ++o) {
        float s = qw[716 + o];
#pragma unroll
        for (int i = 0; i < 12; ++i) s += qw[620 + o*12 + i] * v3[i];
        v4[o] = tanhf_(s);
    }
    float v5[4];
#pragma unroll
    for (int o = 0; o < 4; ++o) {
        float s = qw[756 + o];
#pragma unroll
        for (int i = 0; i < 8; ++i) s += qw[724 + o*8 + i] * v4[i];
        v5[o] = tanhf_(s);
    }
    union { uint32_t u[2]; _Float16 h[4]; } P;
#pragma unroll
    for (int o = 0; o < 4; ++o) {
        float s = qw[776 + o];
#pragma unroll
        for (int i = 0; i < 4; ++i) s += qw[760 + o*4 + i] * v5[i];
        P.h[o] = (_Float16)tanhf_(s);
    }
    *reinterpret_cast<uint2*>(feats + (size_t)r * 4) = make_uint2(P.u[0], P.u[1]);
}

// ---------------- persistent MFMA LSTM: 256 blocks x 256 threads ----------------
// PROVEN operating point (r10, 637us, absmax 9.77e-4): (256,1), arch 252 +
// AGPR 256 both sub-files near-max, asm-pinned q0..3, LDS q4,q5(+q6 tail),
// L2 stream for the rest. (512,2) is ABANDONED: asm-AGPR pinning corrupts
// there (r12/r13: suspected accvgpr-copy-adjacent-to-opaque-asm hazard).
// r14 polish: (1) MFMA_AG0 chain-start (D fresh, C=shared zero) deletes the
// 64 v_mov/step zero-init; (2) per-gate epilogue spread into the next block's
// MFMA shadow; (3) deferred head (r11-proven) emits out[t-1] post-barrier;
// (4) +8KB LDS (q6 tiles 40..47) trims stream 112->104 KB/CU/step.
__global__ __launch_bounds__(256, 1)
void lstm_kernel(const uint4* __restrict__ bfragsG, const _Float16* __restrict__ xwG,
                 const _Float16* __restrict__ feats,
                 const float* __restrict__ f_b, const float* __restrict__ i_b,
                 const float* __restrict__ u_b, const float* __restrict__ o_b,
                 const float* __restrict__ head_w, const float* __restrict__ head_bp,
                 float* __restrict__ out) {
    __shared__ uint4     blds45[2][64][64];          // 131072 B : B q=4,5 all tiles
    __shared__ uint4     blds6o[16][64];             //  16384 B : B q=6, tiles 48..63
    __shared__ uint4     blds6b[8][64];              //   8192 B : B q=6, tiles 40..47
    __shared__ __align__(16) _Float16 comb[2][2][256]; //  2048 B : [buf][sample][k]
    __shared__ float     redL[2][4][2];              //     64 B : [buf][wave][sample]

    const int tid = threadIdx.x;
    const int w   = tid >> 6;          // wave 0..3
    const int l   = tid & 63;
    const int d_  = l >> 4;            // lane's d-slot (0..3)
    const int jl  = (w * 4 + d_) * 16 + (l & 15);   // lane's output dim j
    const int s0  = blockIdx.x * 2;

    // ---- init LDS ----
    for (int idx = tid; idx < 8192; idx += 256) {
        int n = idx >> 7, qq = (idx >> 6) & 1, ll = idx & 63;
        blds45[qq][n][ll] = bfragsG[(n * 8 + 4 + qq) * 64 + ll];
    }
    for (int idx = tid; idx < 1024; idx += 256) {
        int nn = idx >> 6, ll = idx & 63;
        blds6o[nn][ll] = bfragsG[((48 + nn) * 8 + 6) * 64 + ll];
    }
    for (int idx = tid; idx < 512; idx += 256) {
        int nn = idx >> 6, ll = idx & 63;
        blds6b[nn][ll] = bfragsG[((40 + nn) * 8 + 6) * 64 + ll];
    }
    reinterpret_cast<uint32_t*>(&comb[0][0][0])[tid] = 0u;   // h_0 = 0 (buf 0)

    // ---- resident B -> AGPR (exactly 256 regs), q = 0..3 x 16 tiles ----
    f16x8 Br[16][4];
#pragma unroll
    for (int m = 0; m < 16; ++m) {
        const int n = (m >> 2) * 16 + w * 4 + (m & 3);
#pragma unroll
        for (int q = 0; q < 4; ++q) {
            Br[m][q] = *reinterpret_cast<const f16x8*>(bfragsG + (n * 8 + q) * 64 + l);
            asm volatile("" : "+a"(Br[m][q]));
        }
    }

    // ---- per-lane epilogue constants (at jl) ----
    float bias_[4] = { f_b[jl], i_b[jl], u_b[jl], o_b[jl] };
    uint32_t xwp0[4], xwp1[4];
#pragma unroll
    for (int g = 0; g < 4; ++g) {
        union { uint32_t u; _Float16 h[2]; } P;
        P.h[0] = xwG[g*1024 +       jl]; P.h[1] = xwG[g*1024 + 256 + jl];
        xwp0[g] = P.u;
        P.h[0] = xwG[g*1024 + 512 + jl]; P.h[1] = xwG[g*1024 + 768 + jl];
        xwp1[g] = P.u;
    }
    const float hwj = head_w[jl];
    const float hb  = head_bp[0];
    uint2 xr0 = *reinterpret_cast<const uint2*>(feats + ((size_t)0 * BATCH + s0    ) * 4);
    uint2 xr1 = *reinterpret_cast<const uint2*>(feats + ((size_t)0 * BATCH + s0 + 1) * 4);

    const f32x4 z4 = {0.f, 0.f, 0.f, 0.f};   // shared zero C for chain starts

    __syncthreads();

    float cs0 = 0.f, cs1 = 0.f;        // c-state for (jl, sample 0/1)

#pragma unroll 1
    for (int t = 0; t < T_STEPS; ++t) {
        const int cur = t & 1;
        uint2 xn0 = xr0, xn1 = xr1;
        if (t + 1 < T_STEPS) {
            xn0 = *reinterpret_cast<const uint2*>(feats + ((size_t)(t+1) * BATCH + s0    ) * 4);
            xn1 = *reinterpret_cast<const uint2*>(feats + ((size_t)(t+1) * BATCH + s0 + 1) * 4);
        }

        // ---- A fragments (8 x ds_read_b128); row r = sample r&1 ----
        const _Float16* ab = &comb[cur][l & 1][(l >> 4) * 8];
        f16x8 A_[8];
#pragma unroll
        for (int q = 0; q < 8; ++q)
            A_[q] = *reinterpret_cast<const f16x8*>(ab + q * 32);

        float act0[4], act1[4];        // per-gate activations (samples 0,1)

        // ---- 4 gate blocks, ascending q; epilogue spread per block ----
#pragma unroll
        for (int g = 0; g < 4; ++g) {
            // B sources for this block's q6/q7 (LDS where resident, else L2)
            f16x8 s6[4], s7[4];
#pragma unroll
            for (int d = 0; d < 4; ++d) {
                const int n = g * 16 + w * 4 + d;
                if (g == 3)                 s6[d] = *reinterpret_cast<const f16x8*>(&blds6o[w * 4 + d][l]);
                else if (g == 2 && w >= 2)  s6[d] = *reinterpret_cast<const f16x8*>(&blds6b[n - 40][l]);
                else                        s6[d] = *reinterpret_cast<const f16x8*>(bfragsG + (n * 8 + 6) * 64 + l);
                s7[d] = *reinterpret_cast<const f16x8*>(bfragsG + (n * 8 + 7) * 64 + l);
            }
            // LDS q4,q5
            f16x8 b4[4], b5[4];
#pragma unroll
            for (int d = 0; d < 4; ++d) {
                const int n = g * 16 + w * 4 + d;
                b4[d] = *reinterpret_cast<const f16x8*>(&blds45[0][n][l]);
                b5[d] = *reinterpret_cast<const f16x8*>(&blds45[1][n][l]);
            }

            // q0: chain start (D fresh, C = z4) — no zero-init v_movs
            f32x4 c0, c1, c2, c3;
            MFMA_AG0(c0, A_[0], Br[4*g+0][0], z4);
            MFMA_AG0(c1, A_[0], Br[4*g+1][0], z4);
            MFMA_AG0(c2, A_[0], Br[4*g+2][0], z4);
            MFMA_AG0(c3, A_[0], Br[4*g+3][0], z4);
            // q1..3: AGPR-resident accumulate
#pragma unroll
            for (int q = 1; q < 4; ++q) {
                MFMA_AG(c0, A_[q], Br[4*g+0][q]); MFMA_AG(c1, A_[q], Br[4*g+1][q]);
                MFMA_AG(c2, A_[q], Br[4*g+2][q]); MFMA_AG(c3, A_[q], Br[4*g+3][q]);
            }
            // q4..7: intrinsic (compiler-managed waits & hazards)
            c0 = __builtin_amdgcn_mfma_f32_16x16x32_f16(A_[4], b4[0], c0, 0, 0, 0);
            c1 = __builtin_amdgcn_mfma_f32_16x16x32_f16(A_[4], b4[1], c1, 0, 0, 0);
            c2 = __builtin_amdgcn_mfma_f32_16x16x32_f16(A_[4], b4[2], c2, 0, 0, 0);
            c3 = __builtin_amdgcn_mfma_f32_16x16x32_f16(A_[4], b4[3], c3, 0, 0, 0);
            c0 = __builtin_amdgcn_mfma_f32_16x16x32_f16(A_[5], b5[0], c0, 0, 0, 0);
            c1 = __builtin_amdgcn_mfma_f32_16x16x32_f16(A_[5], b5[1], c1, 0, 0, 0);
            c2 = __builtin_amdgcn_mfma_f32_16x16x32_f16(A_[5], b5[2], c2, 0, 0, 0);
            c3 = __builtin_amdgcn_mfma_f32_16x16x32_f16(A_[5], b5[3], c3, 0, 0, 0);
            c0 = __builtin_amdgcn_mfma_f32_16x16x32_f16(A_[6], s6[0], c0, 0, 0, 0);
            c1 = __builtin_amdgcn_mfma_f32_16x16x32_f16(A_[6], s6[1], c1, 0, 0, 0);
            c2 = __builtin_amdgcn_mfma_f32_16x16x32_f16(A_[6], s6[2], c2, 0, 0, 0);
            c3 = __builtin_amdgcn_mfma_f32_16x16x32_f16(A_[6], s6[3], c3, 0, 0, 0);
            c0 = __builtin_amdgcn_mfma_f32_16x16x32_f16(A_[7], s7[0], c0, 0, 0, 0);
            c1 = __builtin_amdgcn_mfma_f32_16x16x32_f16(A_[7], s7[1], c1, 0, 0, 0);
            c2 = __builtin_amdgcn_mfma_f32_16x16x32_f16(A_[7], s7[2], c2, 0, 0, 0);
            c3 = __builtin_amdgcn_mfma_f32_16x16x32_f16(A_[7], s7[3], c3, 0, 0, 0);

            // in-lane select + spread epilogue: this gate's pre-act + activation
            const float gv0 = sel4(d_, c0[0], c1[0], c2[0], c3[0]);
            const float gv1 = sel4(d_, c0[1], c1[1], c2[1], c3[1]);
            const float pg0 = fdot2(xwp0[g], xr0.x, fdot2(xwp1[g], xr0.y, gv0 + bias_[g]));
            const float pg1 = fdot2(xwp0[g], xr1.x, fdot2(xwp1[g], xr1.y, gv1 + bias_[g]));
            if (g == 2) { act0[g] = tanhf_(pg0);    act1[g] = tanhf_(pg1); }
            else        { act0[g] = sigmoidf_(pg0); act1[g] = sigmoidf_(pg1); }
        }

        // ---- final recurrence update (short tail) ----
        cs0 = act0[0] * cs0 + act0[1] * act0[2];
        cs1 = act1[0] * cs1 + act1[1] * act1[2];
        const float h0 = act0[3] * tanhf_(cs0);
        const float h1 = act1[3] * tanhf_(cs1);

        comb[cur ^ 1][0][jl] = (_Float16)h0;
        comb[cur ^ 1][1][jl] = (_Float16)h1;

        xr0 = xn0; xr1 = xn1;
        __syncthreads();                       // one barrier per step

        // ---- deferred head (overlaps next step's MFMA phase; r11-proven) ----
        float p0 = h0 * hwj, p1 = h1 * hwj;
#pragma unroll
        for (int off = 32; off; off >>= 1) {
            p0 += __shfl_xor(p0, off);
            p1 += __shfl_xor(p1, off);
        }
        if (l == 0) { redL[cur][w][0] = p0; redL[cur][w][1] = p1; }

        // out[t-1]: redL[cur^1] was fully written before barrier(t) -> race-free
        if (tid < 2 && t > 0)
            out[(size_t)(t - 1) * BATCH + s0 + tid] =
                (redL[cur ^ 1][0][tid] + redL[cur ^ 1][1][tid]) +
                (redL[cur ^ 1][2][tid] + redL[cur ^ 1][3][tid]) + hb;
    }

    // drain t = 255
    __syncthreads();
    if (tid < 2)
        out[(size_t)(T_STEPS - 1) * BATCH + s0 + tid] =
            (redL[(T_STEPS - 1) & 1][0][tid] + redL[(T_STEPS - 1) & 1][1][tid]) +
            (redL[(T_STEPS - 1) & 1][2][tid] + redL[(T_STEPS - 1) & 1][3][tid]) + hb;
}

extern "C" void kernel_launch(void* const* d_in, const int* in_sizes, int n_in,
                              void* d_out, int out_size, void* d_ws, size_t ws_size,
                              hipStream_t stream) {
    const float* inputs = (const float*)d_in[0];
    const float* fm_w = (const float*)d_in[1];  const float* fm_b = (const float*)d_in[2];
    const float* c1_w = (const float*)d_in[3];  const float* c1_b = (const float*)d_in[4];
    const float* p1_w = (const float*)d_in[5];  const float* p1_b = (const float*)d_in[6];
    const float* c2_w = (const float*)d_in[7];  const float* c2_b = (const float*)d_in[8];
    const float* p2_w = (const float*)d_in[9];  const float* p2_b = (const float*)d_in[10];
    const float* c3_w = (const float*)d_in[11]; const float* c3_b = (const float*)d_in[12];
    const float* f_w  = (const float*)d_in[13]; const float* f_b  = (const float*)d_in[14];
    const float* i_w  = (const float*)d_in[15]; const float* i_b  = (const float*)d_in[16];
    const float* u_w  = (const float*)d_in[17]; const float* u_b  = (const float*)d_in[18];
    const float* o_w  = (const float*)d_in[19]; const float* o_b  = (const float*)d_in[20];
    const float* head_w = (const float*)d_in[21];
    const float* head_b = (const float*)d_in[22];

    // workspace layout (16B aligned)
    uint4*     bfragsG = (uint4*)d_ws;                                // 524288 B
    _Float16*  xwG     = (_Float16*)((char*)d_ws + 524288);           //   8192 B
    _Float16*  feats   = (_Float16*)((char*)d_ws + 532480);           // 1048576 B
    float*     qw      = (float*)((char*)d_ws + 1581056);             //   3120 B

    hipLaunchKernelGGL(concat_qw, dim3(1), dim3(256), 0, stream,
                       fm_w, fm_b, c1_w, c1_b, p1_w, p1_b, c2_w, c2_b,
                       p2_w, p2_b, c3_w, c3_b, qw);
    hipLaunchKernelGGL(pack_bfrag, dim3(128), dim3(256), 0, stream,
                       f_w, i_w, u_w, o_w, bfragsG);
    hipLaunchKernelGGL(pack_xw, dim3(16), dim3(256), 0, stream,
                       f_w, i_w, u_w, o_w, xwG);
    hipLaunchKernelGGL(qcnn_kernel, dim3(512), dim3(256), 0, stream,
                       inputs, qw, feats);
    hipLaunchKernelGGL(lstm_kernel, dim3(256), dim3(256), 0, stream,
                       bfragsG, xwG, feats,
                       f_b, i_b, u_b, o_b, head_w, head_b, (float*)d_out);
}

// Round 15
// 684.611 us; speedup vs baseline: 1.0930x; 1.0930x over previous
//
#include <hip/hip_runtime.h>
#include <hip/hip_bf16.h>
#include <hip/hip_fp16.h>
#include <stdint.h>

#define T_STEPS 256
#define BATCH 512

typedef _Float16 f16x8 __attribute__((ext_vector_type(8)));
typedef _Float16 h2_t  __attribute__((ext_vector_type(2)));
typedef float    f32x4 __attribute__((ext_vector_type(4)));

__device__ __forceinline__ float fdot2(uint32_t w, uint32_t c, float acc) {
#if __has_builtin(__builtin_amdgcn_fdot2)
    h2_t a, b;
    __builtin_memcpy(&a, &w, 4);
    __builtin_memcpy(&b, &c, 4);
    return __builtin_amdgcn_fdot2(a, b, acc, false);
#else
    union { uint32_t u; _Float16 h[2]; } A, B;
    A.u = w; B.u = c;
    return acc + (float)A.h[0]*(float)B.h[0] + (float)A.h[1]*(float)B.h[1];
#endif
}

__device__ __forceinline__ float sigmoidf_(float x) {
    return 1.f / (1.f + __expf(-x));
}
__device__ __forceinline__ float tanhf_(float x) {
    float ax = fabsf(x);
    float e = __expf(-2.f * ax);
    float r = (1.f - e) / (1.f + e);
    return copysignf(r, x);
}

// ---------------- prep: concat QCNN weights ----------------
__global__ void concat_qw(const float* __restrict__ fm_w, const float* __restrict__ fm_b,
                          const float* __restrict__ c1_w, const float* __restrict__ c1_b,
                          const float* __restrict__ p1_w, const float* __restrict__ p1_b,
                          const float* __restrict__ c2_w, const float* __restrict__ c2_b,
                          const float* __restrict__ p2_w, const float* __restrict__ p2_b,
                          const float* __restrict__ c3_w, const float* __restrict__ c3_b,
                          float* __restrict__ qw) {
    for (int k = threadIdx.x; k < 780; k += 256) {
        float v;
        if      (k < 128) v = fm_w[k];
        else if (k < 144) v = fm_b[k-128];
        else if (k < 400) v = c1_w[k-144];
        else if (k < 416) v = c1_b[k-400];
        else if (k < 608) v = p1_w[k-416];
        else if (k < 620) v = p1_b[k-608];
        else if (k < 716) v = c2_w[k-620];
        else if (k < 724) v = c2_b[k-716];
        else if (k < 756) v = p2_w[k-724];
        else if (k < 760) v = p2_b[k-756];
        else if (k < 776) v = c3_w[k-760];
        else              v = c3_b[k-776];
        qw[k] = v;
    }
}

// ---------------- prep: B-fragments (f16) ----------------
// bfragsG[((n*8+q)*64+l)]: N-tile n (col = n*16 + (l&15) = gate*256 + j),
// K-tile q (k = q*32 + (l>>4)*8 + e). k-order errors cancel (A same mapping).
__global__ void pack_bfrag(const float* __restrict__ f_w, const float* __restrict__ i_w,
                           const float* __restrict__ u_w, const float* __restrict__ o_w,
                           uint4* __restrict__ bfragsG) {
    int idx = blockIdx.x * 256 + threadIdx.x;      // 0..32767
    int l = idx & 63, q = (idx >> 6) & 7, n = idx >> 9;
    int col = n * 16 + (l & 15);
    int g = col >> 8, j = col & 255;
    const float* W = (g == 0) ? f_w : (g == 1) ? i_w : (g == 2) ? u_w : o_w;
    union { uint4 u; _Float16 h[8]; } P;
#pragma unroll
    for (int e = 0; e < 8; ++e) {
        int k = q * 32 + ((l >> 4) * 8) + e;       // 0..255 (h part only)
        P.h[e] = (_Float16)W[j * 260 + 4 + k];
    }
    bfragsG[idx] = P.u;
}

// ---------------- prep: x-part weights xwG[g][k][j] f16 ----------------
__global__ void pack_xw(const float* __restrict__ f_w, const float* __restrict__ i_w,
                        const float* __restrict__ u_w, const float* __restrict__ o_w,
                        _Float16* __restrict__ xwG) {
    int t = blockIdx.x * 256 + threadIdx.x;        // 0..4095
    int g = t >> 10, k = (t >> 8) & 3, j = t & 255;
    const float* W = (g == 0) ? f_w : (g == 1) ? i_w : (g == 2) ? u_w : o_w;
    xwG[t] = (_Float16)W[j * 260 + k];
}

// ---------------- QCNN feature extractor ----------------
__global__ void qcnn_kernel(const float* __restrict__ in, const float* __restrict__ qw,
                            _Float16* __restrict__ feats) {
    int r = blockIdx.x * 256 + threadIdx.x;   // 0..131071
    const float* x = in + (size_t)r * 8;
    float v0[8];
#pragma unroll
    for (int i = 0; i < 8; ++i) v0[i] = x[i];
    float v1[16];
#pragma unroll
    for (int o = 0; o < 16; ++o) {
        float s = qw[128 + o];
#pragma unroll
        for (int i = 0; i < 8; ++i) s += qw[o*8 + i] * v0[i];
        v1[o] = tanhf_(s);
    }
    float v2[16];
#pragma unroll
    for (int o = 0; o < 16; ++o) {
        float s = qw[400 + o];
#pragma unroll
        for (int i = 0; i < 16; ++i) s += qw[144 + o*16 + i] * v1[i];
        v2[o] = tanhf_(s);
    }
    float v3[12];
#pragma unroll
    for (int o = 0; o < 12; ++o) {
        float s = qw[608 + o];
#pragma unroll
        for (int i = 0; i < 16; ++i) s += qw[416 + o*16 + i] * v2[i];
        v3[o] = tanhf_(s);
    }
    float v4[8];
#pragma unroll
    for (int o = 0; o < 8; ++o) {
        float s = qw[716 + o];
#pragma unroll
        for (int i = 0; i < 12; ++i) s += qw[620 + o*12 + i] * v3[i];
        v4[o] = tanhf_(s);
    }
    float v5[4];
#pragma unroll
    for (int o = 0; o < 4; ++o) {
        float s = qw[756 + o];
#pragma unroll
        for (int i = 0; i < 8; ++i) s += qw[724 + o*8 + i] * v4[i];
        v5[o] = tanhf_(s);
    }
    union { uint32_t u[2]; _Float16 h[4]; } P;
#pragma unroll
    for (int o = 0; o < 4; ++o) {
        float s = qw[776 + o];
#pragma unroll
        for (int i = 0; i < 4; ++i) s += qw[760 + o*4 + i] * v5[i];
        P.h[o] = (_Float16)tanhf_(s);
    }
    *reinterpret_cast<uint2*>(feats + (size_t)r * 4) = make_uint2(P.u[0], P.u[1]);
}

// ---------------- persistent MFMA LSTM: 256 blocks x 512 threads (8 waves) ----------------
// 2 waves/SIMD (m114: co-resident wave hides the other's latency). This is
// r13's geometry with the ONLY change: every MFMA is the INTRINSIC (the
// r12/r13 corruption is attributed to opaque asm MFMAs blinding the hazard
// recognizer at zero-AGPR-slack; r10 proved the same asm correct at (256,1)
// where slack existed; r1 proved (512,2) implicit-AGPR codegen is correct).
// Br is made non-rematerializable + AGPR-classed by a ONE-TIME empty "+a"
// asm (no instructions -> no hazard surface). Budget/wave: 128 AGPR (Br)
// + ~110 arch <= 256 at 2 waves/SIMD.
// Wave w owns tiles n(g,d) = g*16 + w*2 + d -> j in [w*32, w*32+32).
// B: q0..3 AGPR-resident, q4,q5 L2-streamed (128 KB/CU/step ~ 2300 cy,
// hidden by co-wave), q6,q7 LDS (128 KB). Ascending q0->q7 accumulation
// (same numeric path as r10: absmax 9.77e-4).
__global__ __launch_bounds__(512, 2)
void lstm_kernel(const uint4* __restrict__ bfragsG, const _Float16* __restrict__ xwG,
                 const _Float16* __restrict__ feats,
                 const float* __restrict__ f_b, const float* __restrict__ i_b,
                 const float* __restrict__ u_b, const float* __restrict__ o_b,
                 const float* __restrict__ head_w, const float* __restrict__ head_bp,
                 float* __restrict__ out) {
    __shared__ uint4     blds67[2][64][64];          // 131072 B : B q=6,7 all tiles
    __shared__ __align__(16) _Float16 comb[2][2][256]; //  2048 B : [buf][sample][k]
    __shared__ float     redL[2][8][2];              //    128 B : [buf][wave][sample]

    const int tid = threadIdx.x;
    const int w   = tid >> 6;          // wave 0..7
    const int l   = tid & 63;
    const int smp = l >> 5;            // epilogue sample (0/1)
    const int d_  = (l >> 4) & 1;      // epilogue tile half
    const int jl  = w * 32 + d_ * 16 + (l & 15);    // lane's output dim
    const int s0  = blockIdx.x * 2;

    // ---- init LDS ----
    for (int idx = tid; idx < 8192; idx += 512) {
        int n = idx >> 7, qq = (idx >> 6) & 1, ll = idx & 63;
        blds67[qq][n][ll] = bfragsG[(n * 8 + 6 + qq) * 64 + ll];
    }
    reinterpret_cast<uint32_t*>(&comb[0][0][0])[tid] = 0u;   // zero both h buffers

    // ---- resident B: q0..3 -> AGPR (128 regs), intrinsic-consumed ----
    f16x8 Br[8][4];                    // m = g*2 + d, tile n = (m>>1)*16 + w*2 + (m&1)
#pragma unroll
    for (int m = 0; m < 8; ++m) {
        const int n = (m >> 1) * 16 + w * 2 + (m & 1);
#pragma unroll
        for (int q = 0; q < 4; ++q) {
            Br[m][q] = *reinterpret_cast<const f16x8*>(bfragsG + (n * 8 + q) * 64 + l);
            // one-time class pin: AGPR, non-rematerializable; emits no insts
            asm volatile("" : "+a"(Br[m][q]));
        }
    }

    // ---- per-lane epilogue constants (dim jl, sample smp) ----
    float bias_[4] = { f_b[jl], i_b[jl], u_b[jl], o_b[jl] };
    uint32_t xwp0[4], xwp1[4];
#pragma unroll
    for (int g = 0; g < 4; ++g) {
        union { uint32_t u; _Float16 h[2]; } P;
        P.h[0] = xwG[g*1024 +       jl]; P.h[1] = xwG[g*1024 + 256 + jl];
        xwp0[g] = P.u;
        P.h[0] = xwG[g*1024 + 512 + jl]; P.h[1] = xwG[g*1024 + 768 + jl];
        xwp1[g] = P.u;
    }
    const float hwj = head_w[jl];
    const float hb  = head_bp[0];

    __syncthreads();

    float cs = 0.f;                    // c-state for (jl, smp)

#pragma unroll 1
    for (int t = 0; t < T_STEPS; ++t) {
        const int cur = t & 1;
        // x_t for this lane's sample (8B broadcast load; consumed in epilogue)
        const uint2 xr = *reinterpret_cast<const uint2*>(
            feats + ((size_t)t * BATCH + s0 + smp) * 4);

        // ---- A fragments (8 x ds_read_b128); row r = sample r&1 ----
        const _Float16* ab = &comb[cur][l & 1][(l >> 4) * 8];
        f16x8 A_[8];
#pragma unroll
        for (int q = 0; q < 8; ++q)
            A_[q] = *reinterpret_cast<const f16x8*>(ab + q * 32);

        float pre[4];

        // ---- 4 gate blocks (2 tiles each), strictly ascending q ----
#pragma unroll
        for (int g = 0; g < 4; ++g) {
            const int n0 = g * 16 + w * 2;
            const int n1 = n0 + 1;
            // L2-streamed q4,q5 (issued at block top; consumed after 8
            // resident MFMAs; co-wave overlap covers the remaining latency)
            f16x8 s4a = *reinterpret_cast<const f16x8*>(bfragsG + (n0 * 8 + 4) * 64 + l);
            f16x8 s4b = *reinterpret_cast<const f16x8*>(bfragsG + (n1 * 8 + 4) * 64 + l);
            f16x8 s5a = *reinterpret_cast<const f16x8*>(bfragsG + (n0 * 8 + 5) * 64 + l);
            f16x8 s5b = *reinterpret_cast<const f16x8*>(bfragsG + (n1 * 8 + 5) * 64 + l);

            f32x4 c0 = {0.f, 0.f, 0.f, 0.f};
            f32x4 c1 = {0.f, 0.f, 0.f, 0.f};

            // q0..3: AGPR-resident (intrinsics — hazards compiler-managed)
#pragma unroll
            for (int q = 0; q < 4; ++q) {
                c0 = __builtin_amdgcn_mfma_f32_16x16x32_f16(A_[q], Br[2*g    ][q], c0, 0, 0, 0);
                c1 = __builtin_amdgcn_mfma_f32_16x16x32_f16(A_[q], Br[2*g + 1][q], c1, 0, 0, 0);
            }
            // q4,q5: L2-streamed
            c0 = __builtin_amdgcn_mfma_f32_16x16x32_f16(A_[4], s4a, c0, 0, 0, 0);
            c1 = __builtin_amdgcn_mfma_f32_16x16x32_f16(A_[4], s4b, c1, 0, 0, 0);
            c0 = __builtin_amdgcn_mfma_f32_16x16x32_f16(A_[5], s5a, c0, 0, 0, 0);
            c1 = __builtin_amdgcn_mfma_f32_16x16x32_f16(A_[5], s5b, c1, 0, 0, 0);
            // q6,q7: LDS, reads adjacent to use
            f16x8 t6a = *reinterpret_cast<const f16x8*>(&blds67[0][n0][l]);
            f16x8 t6b = *reinterpret_cast<const f16x8*>(&blds67[0][n1][l]);
            c0 = __builtin_amdgcn_mfma_f32_16x16x32_f16(A_[6], t6a, c0, 0, 0, 0);
            c1 = __builtin_amdgcn_mfma_f32_16x16x32_f16(A_[6], t6b, c1, 0, 0, 0);
            f16x8 t7a = *reinterpret_cast<const f16x8*>(&blds67[1][n0][l]);
            f16x8 t7b = *reinterpret_cast<const f16x8*>(&blds67[1][n1][l]);
            c0 = __builtin_amdgcn_mfma_f32_16x16x32_f16(A_[7], t7a, c0, 0, 0, 0);
            c1 = __builtin_amdgcn_mfma_f32_16x16x32_f16(A_[7], t7b, c1, 0, 0, 0);

            // C reg index = sample (row = (l>>4)*4 + reg, sample = reg&1); tile by d_
            const float va = smp ? c0[1] : c0[0];
            const float vb = smp ? c1[1] : c1[0];
            pre[g] = (d_ ? vb : va) + bias_[g];
        }

        // ---- epilogue: 1 (jl, smp) update per lane ----
        float p0 = fdot2(xwp0[0], xr.x, fdot2(xwp1[0], xr.y, pre[0]));
        float p1 = fdot2(xwp0[1], xr.x, fdot2(xwp1[1], xr.y, pre[1]));
        float p2 = fdot2(xwp0[2], xr.x, fdot2(xwp1[2], xr.y, pre[2]));
        float p3 = fdot2(xwp0[3], xr.x, fdot2(xwp1[3], xr.y, pre[3]));
        const float fg = sigmoidf_(p0);
        const float ig = sigmoidf_(p1);
        const float ug = tanhf_(p2);
        const float og = sigmoidf_(p3);
        cs = fg * cs + ig * ug;
        const float h = og * tanhf_(cs);

        comb[cur ^ 1][smp][jl] = (_Float16)h;

        __syncthreads();                       // one barrier per step

        // ---- deferred head (overlaps next step's MFMA phase) ----
        float p = h * hwj;
        p += __shfl_xor(p, 1);
        p += __shfl_xor(p, 2);
        p += __shfl_xor(p, 4);
        p += __shfl_xor(p, 8);
        p += __shfl_xor(p, 16);                // reduce 32-lane half (one sample)
        if ((l & 31) == 0) redL[cur][w][smp] = p;

        // out[t-1]: redL[cur^1] writes finished before barrier(t) -> race-free
        if (tid < 2 && t > 0) {
            float acc = hb;
#pragma unroll
            for (int ww = 0; ww < 8; ++ww) acc += redL[cur ^ 1][ww][tid];
            out[(size_t)(t - 1) * BATCH + s0 + tid] = acc;
        }
    }

    // drain t = 255
    __syncthreads();
    if (tid < 2) {
        float acc = hb;
#pragma unroll
        for (int ww = 0; ww < 8; ++ww) acc += redL[(T_STEPS - 1) & 1][ww][tid];
        out[(size_t)(T_STEPS - 1) * BATCH + s0 + tid] = acc;
    }
}

extern "C" void kernel_launch(void* const* d_in, const int* in_sizes, int n_in,
                              void* d_out, int out_size, void* d_ws, size_t ws_size,
                              hipStream_t stream) {
    const float* inputs = (const float*)d_in[0];
    const float* fm_w = (const float*)d_in[1];  const float* fm_b = (const float*)d_in[2];
    const float* c1_w = (const float*)d_in[3];  const float* c1_b = (const float*)d_in[4];
    const float* p1_w = (const float*)d_in[5];  const float* p1_b = (const float*)d_in[6];
    const float* c2_w = (const float*)d_in[7];  const float* c2_b = (const float*)d_in[8];
    const float* p2_w = (const float*)d_in[9];  const float* p2_b = (const float*)d_in[10];
    const float* c3_w = (const float*)d_in[11]; const float* c3_b = (const float*)d_in[12];
    const float* f_w  = (const float*)d_in[13]; const float* f_b  = (const float*)d_in[14];
    const float* i_w  = (const float*)d_in[15]; const float* i_b  = (const float*)d_in[16];
    const float* u_w  = (const float*)d_in[17]; const float* u_b  = (const float*)d_in[18];
    const float* o_w  = (const float*)d_in[19]; const float* o_b  = (const float*)d_in[20];
    const float* head_w = (const float*)d_in[21];
    const float* head_b = (const float*)d_in[22];

    // workspace layout (16B aligned)
    uint4*     bfragsG = (uint4*)d_ws;                                // 524288 B
    _Float16*  xwG     = (_Float16*)((char*)d_ws + 524288);           //   8192 B
    _Float16*  feats   = (_Float16*)((char*)d_ws + 532480);           // 1048576 B
    float*     qw      = (float*)((char*)d_ws + 1581056);             //   3120 B

    hipLaunchKernelGGL(concat_qw, dim3(1), dim3(256), 0, stream,
                       fm_w, fm_b, c1_w, c1_b, p1_w, p1_b, c2_w, c2_b,
                       p2_w, p2_b, c3_w, c3_b, qw);
    hipLaunchKernelGGL(pack_bfrag, dim3(128), dim3(256), 0, stream,
                       f_w, i_w, u_w, o_w, bfragsG);
    hipLaunchKernelGGL(pack_xw, dim3(16), dim3(256), 0, stream,
                       f_w, i_w, u_w, o_w, xwG);
    hipLaunchKernelGGL(qcnn_kernel, dim3(512), dim3(256), 0, stream,
                       inputs, qw, feats);
    hipLaunchKernelGGL(lstm_kernel, dim3(256), dim3(512), 0, stream,
                       bfragsG, xwG, feats,
                       f_b, i_b, u_b, o_b, head_w, head_b, (float*)d_out);
}

// Round 16
// 662.328 us; speedup vs baseline: 1.1297x; 1.0336x over previous
//
#include <hip/hip_runtime.h>
#include <hip/hip_bf16.h>
#include <hip/hip_fp16.h>
#include <stdint.h>

#define T_STEPS 256
#define BATCH 512

typedef _Float16 f16x8 __attribute__((ext_vector_type(8)));
typedef _Float16 h2_t  __attribute__((ext_vector_type(2)));
typedef float    f32x4 __attribute__((ext_vector_type(4)));

__device__ __forceinline__ float fdot2(uint32_t w, uint32_t c, float acc) {
#if __has_builtin(__builtin_amdgcn_fdot2)
    h2_t a, b;
    __builtin_memcpy(&a, &w, 4);
    __builtin_memcpy(&b, &c, 4);
    return __builtin_amdgcn_fdot2(a, b, acc, false);
#else
    union { uint32_t u; _Float16 h[2]; } A, B;
    A.u = w; B.u = c;
    return acc + (float)A.h[0]*(float)B.h[0] + (float)A.h[1]*(float)B.h[1];
#endif
}

__device__ __forceinline__ float sigmoidf_(float x) {
    return 1.f / (1.f + __expf(-x));
}
__device__ __forceinline__ float tanhf_(float x) {
    float ax = fabsf(x);
    float e = __expf(-2.f * ax);
    float r = (1.f - e) / (1.f + e);
    return copysignf(r, x);
}

// pick-of-4 by d (0..3) without runtime array indexing (3 cndmask)
__device__ __forceinline__ float sel4(int d, float a, float b, float c, float e) {
    float lo = (d & 1) ? b : a;
    float hi = (d & 1) ? e : c;
    return (d & 2) ? hi : lo;
}

// resident-B MFMA: B pinned in AGPR via "a" constraint
#define MFMA_AG(c, aa, bb) \
    asm volatile("v_mfma_f32_16x16x32_f16 %0, %1, %2, %0" : "+v"(c) : "v"(aa), "a"(bb))

// ---------------- prep: concat QCNN weights ----------------
__global__ void concat_qw(const float* __restrict__ fm_w, const float* __restrict__ fm_b,
                          const float* __restrict__ c1_w, const float* __restrict__ c1_b,
                          const float* __restrict__ p1_w, const float* __restrict__ p1_b,
                          const float* __restrict__ c2_w, const float* __restrict__ c2_b,
                          const float* __restrict__ p2_w, const float* __restrict__ p2_b,
                          const float* __restrict__ c3_w, const float* __restrict__ c3_b,
                          float* __restrict__ qw) {
    for (int k = threadIdx.x; k < 780; k += 256) {
        float v;
        if      (k < 128) v = fm_w[k];
        else if (k < 144) v = fm_b[k-128];
        else if (k < 400) v = c1_w[k-144];
        else if (k < 416) v = c1_b[k-400];
        else if (k < 608) v = p1_w[k-416];
        else if (k < 620) v = p1_b[k-608];
        else if (k < 716) v = c2_w[k-620];
        else if (k < 724) v = c2_b[k-716];
        else if (k < 756) v = p2_w[k-724];
        else if (k < 760) v = p2_b[k-756];
        else if (k < 776) v = c3_w[k-760];
        else              v = c3_b[k-776];
        qw[k] = v;
    }
}

// ---------------- prep: B-fragments (f16) ----------------
// bfragsG[((n*8+q)*64+l)]: N-tile n (col = n*16 + (l&15) = gate*256 + j),
// K-tile q (k = q*32 + (l>>4)*8 + e). k-order errors cancel (A same mapping).
__global__ void pack_bfrag(const float* __restrict__ f_w, const float* __restrict__ i_w,
                           const float* __restrict__ u_w, const float* __restrict__ o_w,
                           uint4* __restrict__ bfragsG) {
    int idx = blockIdx.x * 256 + threadIdx.x;      // 0..32767
    int l = idx & 63, q = (idx >> 6) & 7, n = idx >> 9;
    int col = n * 16 + (l & 15);
    int g = col >> 8, j = col & 255;
    const float* W = (g == 0) ? f_w : (g == 1) ? i_w : (g == 2) ? u_w : o_w;
    union { uint4 u; _Float16 h[8]; } P;
#pragma unroll
    for (int e = 0; e < 8; ++e) {
        int k = q * 32 + ((l >> 4) * 8) + e;       // 0..255 (h part only)
        P.h[e] = (_Float16)W[j * 260 + 4 + k];
    }
    bfragsG[idx] = P.u;
}

// ---------------- prep: x-part weights xwG[g][k][j] f16 ----------------
__global__ void pack_xw(const float* __restrict__ f_w, const float* __restrict__ i_w,
                        const float* __restrict__ u_w, const float* __restrict__ o_w,
                        _Float16* __restrict__ xwG) {
    int t = blockIdx.x * 256 + threadIdx.x;        // 0..4095
    int g = t >> 10, k = (t >> 8) & 3, j = t & 255;
    const float* W = (g == 0) ? f_w : (g == 1) ? i_w : (g == 2) ? u_w : o_w;
    xwG[t] = (_Float16)W[j * 260 + k];
}

// ---------------- QCNN feature extractor ----------------
__global__ void qcnn_kernel(const float* __restrict__ in, const float* __restrict__ qw,
                            _Float16* __restrict__ feats) {
    int r = blockIdx.x * 256 + threadIdx.x;   // 0..131071
    const float* x = in + (size_t)r * 8;
    float v0[8];
#pragma unroll
    for (int i = 0; i < 8; ++i) v0[i] = x[i];
    float v1[16];
#pragma unroll
    for (int o = 0; o < 16; ++o) {
        float s = qw[128 + o];
#pragma unroll
        for (int i = 0; i < 8; ++i) s += qw[o*8 + i] * v0[i];
        v1[o] = tanhf_(s);
    }
    float v2[16];
#pragma unroll
    for (int o = 0; o < 16; ++o) {
        float s = qw[400 + o];
#pragma unroll
        for (int i = 0; i < 16; ++i) s += qw[144 + o*16 + i] * v1[i];
        v2[o] = tanhf_(s);
    }
    float v3[12];
#pragma unroll
    for (int o = 0; o < 12; ++o) {
        float s = qw[608 + o];
#pragma unroll
        for (int i = 0; i < 16; ++i) s += qw[416 + o*16 + i] * v2[i];
        v3[o] = tanhf_(s);
    }
    float v4[8];
#pragma unroll
    for (int o = 0; o < 8; ++o) {
        float s = qw[716 + o];
#pragma unroll
        for (int i = 0; i < 12; ++i) s += qw[620 + o*12 + i] * v3[i];
        v4[o] = tanhf_(s);
    }
    float v5[4];
#pragma unroll
    for (int o = 0; o < 4; ++o) {
        float s = qw[756 + o];
#pragma unroll
        for (int i = 0; i < 8; ++i) s += qw[724 + o*8 + i] * v4[i];
        v5[o] = tanhf_(s);
    }
    union { uint32_t u[2]; _Float16 h[4]; } P;
#pragma unroll
    for (int o = 0; o < 4; ++o) {
        float s = qw[776 + o];
#pragma unroll
        for (int i = 0; i < 4; ++i) s += qw[760 + o*4 + i] * v5[i];
        P.h[o] = (_Float16)tanhf_(s);
    }
    *reinterpret_cast<uint2*>(feats + (size_t)r * 4) = make_uint2(P.u[0], P.u[1]);
}

// ---------------- persistent MFMA LSTM: 256 blocks x 256 threads ----------------
// This is the PROVEN best operating point (r10, 637us, absmax 9.77e-4):
// (256,1), arch 252 + AGPR 256 (both sub-files near-max, budget closes),
// asm-pinned q0..3 in AGPR, LDS q4,q5 + q6-of-gate-o, L2 stream q6(f/i/u)+q7,
// in-lane epilogue via C-reg sample parity + sel4. The ONLY change vs r10:
// the head reduce is DEFERRED past the barrier (r14/r15-validated sync:
// out[t-1] from redL[cur^1], post-loop drain) -> ~200 cy of dependent
// shuffles move off the per-step critical path into the next MFMA shadow.
// Series evidence: 2-wave/SIMD (r15: occupancy 2x, SAME speed) and
// all-resident-B (r11) both failed to beat this point -> the residue above
// the 2176-cy/SIMD MFMA floor is the serial step structure itself.
__global__ __launch_bounds__(256, 1)
void lstm_kernel(const uint4* __restrict__ bfragsG, const _Float16* __restrict__ xwG,
                 const _Float16* __restrict__ feats,
                 const float* __restrict__ f_b, const float* __restrict__ i_b,
                 const float* __restrict__ u_b, const float* __restrict__ o_b,
                 const float* __restrict__ head_w, const float* __restrict__ head_bp,
                 float* __restrict__ out) {
    __shared__ uint4     blds45[2][64][64];          // 131072 B : B q=4,5 all tiles
    __shared__ uint4     blds6o[16][64];             //  16384 B : B q=6, tiles 48..63
    __shared__ __align__(16) _Float16 comb[2][2][256]; //  2048 B : [buf][sample][k]
    __shared__ float     redL[2][4][2];              //     64 B : [buf][wave][sample]

    const int tid = threadIdx.x;
    const int w   = tid >> 6;          // wave 0..3
    const int l   = tid & 63;
    const int d_  = l >> 4;            // lane's d-slot (0..3)
    const int jl  = (w * 4 + d_) * 16 + (l & 15);   // lane's output dim j
    const int s0  = blockIdx.x * 2;

    // ---- init LDS ----
    for (int idx = tid; idx < 8192; idx += 256) {
        int n = idx >> 7, qq = (idx >> 6) & 1, ll = idx & 63;
        blds45[qq][n][ll] = bfragsG[(n * 8 + 4 + qq) * 64 + ll];
    }
    for (int idx = tid; idx < 1024; idx += 256) {
        int nn = idx >> 6, ll = idx & 63;
        blds6o[nn][ll] = bfragsG[((48 + nn) * 8 + 6) * 64 + ll];
    }
    reinterpret_cast<uint32_t*>(&comb[0][0][0])[tid] = 0u;   // h_0 = 0 (buf 0)

    // ---- resident B -> AGPR (exactly 256 regs), q = 0..3 x 16 tiles ----
    f16x8 Br[16][4];
#pragma unroll
    for (int m = 0; m < 16; ++m) {
        const int n = (m >> 2) * 16 + w * 4 + (m & 3);
#pragma unroll
        for (int q = 0; q < 4; ++q) {
            Br[m][q] = *reinterpret_cast<const f16x8*>(bfragsG + (n * 8 + q) * 64 + l);
            asm volatile("" : "+a"(Br[m][q]));
        }
    }

    // ---- per-lane epilogue constants (at jl) ----
    float bias_[4] = { f_b[jl], i_b[jl], u_b[jl], o_b[jl] };
    uint32_t xwp0[4], xwp1[4];
#pragma unroll
    for (int g = 0; g < 4; ++g) {
        union { uint32_t u; _Float16 h[2]; } P;
        P.h[0] = xwG[g*1024 +       jl]; P.h[1] = xwG[g*1024 + 256 + jl];
        xwp0[g] = P.u;
        P.h[0] = xwG[g*1024 + 512 + jl]; P.h[1] = xwG[g*1024 + 768 + jl];
        xwp1[g] = P.u;
    }
    const float hwj = head_w[jl];
    const float hb  = head_bp[0];
    uint2 xr0 = *reinterpret_cast<const uint2*>(feats + ((size_t)0 * BATCH + s0    ) * 4);
    uint2 xr1 = *reinterpret_cast<const uint2*>(feats + ((size_t)0 * BATCH + s0 + 1) * 4);

    __syncthreads();

    float cs0 = 0.f, cs1 = 0.f;        // c-state for (jl, sample 0/1)

#pragma unroll 1
    for (int t = 0; t < T_STEPS; ++t) {
        const int cur = t & 1;
        uint2 xn0 = xr0, xn1 = xr1;
        if (t + 1 < T_STEPS) {
            xn0 = *reinterpret_cast<const uint2*>(feats + ((size_t)(t+1) * BATCH + s0    ) * 4);
            xn1 = *reinterpret_cast<const uint2*>(feats + ((size_t)(t+1) * BATCH + s0 + 1) * 4);
        }

        // ---- A fragments (8 x ds_read_b128); row r = sample r&1 ----
        const _Float16* ab = &comb[cur][l & 1][(l >> 4) * 8];
        f16x8 A_[8];
#pragma unroll
        for (int q = 0; q < 8; ++q)
            A_[q] = *reinterpret_cast<const f16x8*>(ab + q * 32);

        float gv0[4], gv1[4];          // selected gate values (samples 0,1)

        // ---- 4 gate blocks, ascending q within each ----
#pragma unroll
        for (int g = 0; g < 4; ++g) {
            // stream loads for this block (consumed at q6/q7, >=20 MFMAs later)
            f16x8 s6[4], s7[4];
#pragma unroll
            for (int d = 0; d < 4; ++d) {
                const int n = g * 16 + w * 4 + d;
                if (g < 3) s6[d] = *reinterpret_cast<const f16x8*>(bfragsG + (n * 8 + 6) * 64 + l);
                else       s6[d] = *reinterpret_cast<const f16x8*>(&blds6o[w * 4 + d][l]);
                s7[d] = *reinterpret_cast<const f16x8*>(bfragsG + (n * 8 + 7) * 64 + l);
            }
            // LDS q4,q5
            f16x8 b4[4], b5[4];
#pragma unroll
            for (int d = 0; d < 4; ++d) {
                const int n = g * 16 + w * 4 + (d & 3);
                b4[d] = *reinterpret_cast<const f16x8*>(&blds45[0][n][l]);
                b5[d] = *reinterpret_cast<const f16x8*>(&blds45[1][n][l]);
            }

            f32x4 c0 = {0.f,0.f,0.f,0.f}, c1 = {0.f,0.f,0.f,0.f};
            f32x4 c2 = {0.f,0.f,0.f,0.f}, c3 = {0.f,0.f,0.f,0.f};
            asm volatile("s_nop 0" : "+v"(c0), "+v"(c1), "+v"(c2), "+v"(c3));

            // q0..3: AGPR-resident (asm)
#pragma unroll
            for (int q = 0; q < 4; ++q) {
                MFMA_AG(c0, A_[q], Br[4*g+0][q]); MFMA_AG(c1, A_[q], Br[4*g+1][q]);
                MFMA_AG(c2, A_[q], Br[4*g+2][q]); MFMA_AG(c3, A_[q], Br[4*g+3][q]);
            }
            // q4..7: intrinsic (compiler-managed waits & hazards)
            c0 = __builtin_amdgcn_mfma_f32_16x16x32_f16(A_[4], b4[0], c0, 0, 0, 0);
            c1 = __builtin_amdgcn_mfma_f32_16x16x32_f16(A_[4], b4[1], c1, 0, 0, 0);
            c2 = __builtin_amdgcn_mfma_f32_16x16x32_f16(A_[4], b4[2], c2, 0, 0, 0);
            c3 = __builtin_amdgcn_mfma_f32_16x16x32_f16(A_[4], b4[3], c3, 0, 0, 0);
            c0 = __builtin_amdgcn_mfma_f32_16x16x32_f16(A_[5], b5[0], c0, 0, 0, 0);
            c1 = __builtin_amdgcn_mfma_f32_16x16x32_f16(A_[5], b5[1], c1, 0, 0, 0);
            c2 = __builtin_amdgcn_mfma_f32_16x16x32_f16(A_[5], b5[2], c2, 0, 0, 0);
            c3 = __builtin_amdgcn_mfma_f32_16x16x32_f16(A_[5], b5[3], c3, 0, 0, 0);
            c0 = __builtin_amdgcn_mfma_f32_16x16x32_f16(A_[6], s6[0], c0, 0, 0, 0);
            c1 = __builtin_amdgcn_mfma_f32_16x16x32_f16(A_[6], s6[1], c1, 0, 0, 0);
            c2 = __builtin_amdgcn_mfma_f32_16x16x32_f16(A_[6], s6[2], c2, 0, 0, 0);
            c3 = __builtin_amdgcn_mfma_f32_16x16x32_f16(A_[6], s6[3], c3, 0, 0, 0);
            c0 = __builtin_amdgcn_mfma_f32_16x16x32_f16(A_[7], s7[0], c0, 0, 0, 0);
            c1 = __builtin_amdgcn_mfma_f32_16x16x32_f16(A_[7], s7[1], c1, 0, 0, 0);
            c2 = __builtin_amdgcn_mfma_f32_16x16x32_f16(A_[7], s7[2], c2, 0, 0, 0);
            c3 = __builtin_amdgcn_mfma_f32_16x16x32_f16(A_[7], s7[3], c3, 0, 0, 0);

            // in-lane select: lane's d-slot picks its tile; regs 0/1 = samples 0/1
            gv0[g] = sel4(d_, c0[0], c1[0], c2[0], c3[0]);
            gv1[g] = sel4(d_, c0[1], c1[1], c2[1], c3[1]);
        }

        // ---- epilogue: all in-register, lane owns (jl, s=0) and (jl, s=1) ----
        float pre0[4], pre1[4];
#pragma unroll
        for (int g = 0; g < 4; ++g) {
            pre0[g] = fdot2(xwp0[g], xr0.x, fdot2(xwp1[g], xr0.y, gv0[g] + bias_[g]));
            pre1[g] = fdot2(xwp0[g], xr1.x, fdot2(xwp1[g], xr1.y, gv1[g] + bias_[g]));
        }
        const float fg0 = sigmoidf_(pre0[0]), fg1 = sigmoidf_(pre1[0]);
        const float ig0 = sigmoidf_(pre0[1]), ig1 = sigmoidf_(pre1[1]);
        const float ug0 = tanhf_(pre0[2]),    ug1 = tanhf_(pre1[2]);
        const float og0 = sigmoidf_(pre0[3]), og1 = sigmoidf_(pre1[3]);
        cs0 = fg0 * cs0 + ig0 * ug0;
        cs1 = fg1 * cs1 + ig1 * ug1;
        const float h0 = og0 * tanhf_(cs0);
        const float h1 = og1 * tanhf_(cs1);

        comb[cur ^ 1][0][jl] = (_Float16)h0;
        comb[cur ^ 1][1][jl] = (_Float16)h1;

        xr0 = xn0; xr1 = xn1;
        __syncthreads();                       // one barrier per step

        // ---- deferred head (off the critical path; overlaps next MFMA phase) ----
        float p0 = h0 * hwj, p1 = h1 * hwj;
#pragma unroll
        for (int off = 32; off; off >>= 1) {
            p0 += __shfl_xor(p0, off);
            p1 += __shfl_xor(p1, off);
        }
        if (l == 0) { redL[cur][w][0] = p0; redL[cur][w][1] = p1; }

        // out[t-1]: redL[cur^1] (written post-barrier(t-1)) is separated from
        // this read by barrier(t); overwrite of that slot happens post-barrier(t+1)
        if (tid < 2 && t > 0)
            out[(size_t)(t - 1) * BATCH + s0 + tid] =
                (redL[cur ^ 1][0][tid] + redL[cur ^ 1][1][tid]) +
                (redL[cur ^ 1][2][tid] + redL[cur ^ 1][3][tid]) + hb;
    }

    // drain t = 255
    __syncthreads();
    if (tid < 2)
        out[(size_t)(T_STEPS - 1) * BATCH + s0 + tid] =
            (redL[(T_STEPS - 1) & 1][0][tid] + redL[(T_STEPS - 1) & 1][1][tid]) +
            (redL[(T_STEPS - 1) & 1][2][tid] + redL[(T_STEPS - 1) & 1][3][tid]) + hb;
}

extern "C" void kernel_launch(void* const* d_in, const int* in_sizes, int n_in,
                              void* d_out, int out_size, void* d_ws, size_t ws_size,
                              hipStream_t stream) {
    const float* inputs = (const float*)d_in[0];
    const float* fm_w = (const float*)d_in[1];  const float* fm_b = (const float*)d_in[2];
    const float* c1_w = (const float*)d_in[3];  const float* c1_b = (const float*)d_in[4];
    const float* p1_w = (const float*)d_in[5];  const float* p1_b = (const float*)d_in[6];
    const float* c2_w = (const float*)d_in[7];  const float* c2_b = (const float*)d_in[8];
    const float* p2_w = (const float*)d_in[9];  const float* p2_b = (const float*)d_in[10];
    const float* c3_w = (const float*)d_in[11]; const float* c3_b = (const float*)d_in[12];
    const float* f_w  = (const float*)d_in[13]; const float* f_b  = (const float*)d_in[14];
    const float* i_w  = (const float*)d_in[15]; const float* i_b  = (const float*)d_in[16];
    const float* u_w  = (const float*)d_in[17]; const float* u_b  = (const float*)d_in[18];
    const float* o_w  = (const float*)d_in[19]; const float* o_b  = (const float*)d_in[20];
    const float* head_w = (const float*)d_in[21];
    const float* head_b = (const float*)d_in[22];

    // workspace layout (16B aligned)
    uint4*     bfragsG = (uint4*)d_ws;                                // 524288 B
    _Float16*  xwG     = (_Float16*)((char*)d_ws + 524288);           //   8192 B
    _Float16*  feats   = (_Float16*)((char*)d_ws + 532480);           // 1048576 B
    float*     qw      = (float*)((char*)d_ws + 1581056);             //   3120 B

    hipLaunchKernelGGL(concat_qw, dim3(1), dim3(256), 0, stream,
                       fm_w, fm_b, c1_w, c1_b, p1_w, p1_b, c2_w, c2_b,
                       p2_w, p2_b, c3_w, c3_b, qw);
    hipLaunchKernelGGL(pack_bfrag, dim3(128), dim3(256), 0, stream,
                       f_w, i_w, u_w, o_w, bfragsG);
    hipLaunchKernelGGL(pack_xw, dim3(16), dim3(256), 0, stream,
                       f_w, i_w, u_w, o_w, xwG);
    hipLaunchKernelGGL(qcnn_kernel, dim3(512), dim3(256), 0, stream,
                       inputs, qw, feats);
    hipLaunchKernelGGL(lstm_kernel, dim3(256), dim3(256), 0, stream,
                       bfragsG, xwG, feats,
                       f_b, i_b, u_b, o_b, head_w, head_b, (float*)d_out);
}

// Round 17
// 634.858 us; speedup vs baseline: 1.1786x; 1.0433x over previous
//
#include <hip/hip_runtime.h>
#include <hip/hip_bf16.h>
#include <hip/hip_fp16.h>
#include <stdint.h>

#define T_STEPS 256
#define BATCH 512

typedef _Float16 f16x8 __attribute__((ext_vector_type(8)));
typedef _Float16 h2_t  __attribute__((ext_vector_type(2)));
typedef float    f32x4 __attribute__((ext_vector_type(4)));

__device__ __forceinline__ float fdot2(uint32_t w, uint32_t c, float acc) {
#if __has_builtin(__builtin_amdgcn_fdot2)
    h2_t a, b;
    __builtin_memcpy(&a, &w, 4);
    __builtin_memcpy(&b, &c, 4);
    return __builtin_amdgcn_fdot2(a, b, acc, false);
#else
    union { uint32_t u; _Float16 h[2]; } A, B;
    A.u = w; B.u = c;
    return acc + (float)A.h[0]*(float)B.h[0] + (float)A.h[1]*(float)B.h[1];
#endif
}

__device__ __forceinline__ float sigmoidf_(float x) {
    return 1.f / (1.f + __expf(-x));
}
__device__ __forceinline__ float tanhf_(float x) {
    float ax = fabsf(x);
    float e = __expf(-2.f * ax);
    float r = (1.f - e) / (1.f + e);
    return copysignf(r, x);
}

// pick-of-4 by d (0..3) without runtime array indexing (3 cndmask)
__device__ __forceinline__ float sel4(int d, float a, float b, float c, float e) {
    float lo = (d & 1) ? b : a;
    float hi = (d & 1) ? e : c;
    return (d & 2) ? hi : lo;
}

// resident-B MFMA: B pinned in AGPR via "a" constraint
#define MFMA_AG(c, aa, bb) \
    asm volatile("v_mfma_f32_16x16x32_f16 %0, %1, %2, %0" : "+v"(c) : "v"(aa), "a"(bb))

// ---------------- prep: concat QCNN weights ----------------
__global__ void concat_qw(const float* __restrict__ fm_w, const float* __restrict__ fm_b,
                          const float* __restrict__ c1_w, const float* __restrict__ c1_b,
                          const float* __restrict__ p1_w, const float* __restrict__ p1_b,
                          const float* __restrict__ c2_w, const float* __restrict__ c2_b,
                          const float* __restrict__ p2_w, const float* __restrict__ p2_b,
                          const float* __restrict__ c3_w, const float* __restrict__ c3_b,
                          float* __restrict__ qw) {
    for (int k = threadIdx.x; k < 780; k += 256) {
        float v;
        if      (k < 128) v = fm_w[k];
        else if (k < 144) v = fm_b[k-128];
        else if (k < 400) v = c1_w[k-144];
        else if (k < 416) v = c1_b[k-400];
        else if (k < 608) v = p1_w[k-416];
        else if (k < 620) v = p1_b[k-608];
        else if (k < 716) v = c2_w[k-620];
        else if (k < 724) v = c2_b[k-716];
        else if (k < 756) v = p2_w[k-724];
        else if (k < 760) v = p2_b[k-756];
        else if (k < 776) v = c3_w[k-760];
        else              v = c3_b[k-776];
        qw[k] = v;
    }
}

// ---------------- prep: B-fragments (f16) ----------------
// bfragsG[((n*8+q)*64+l)]: N-tile n (col = n*16 + (l&15) = gate*256 + j),
// K-tile q (k = q*32 + (l>>4)*8 + e). k-order errors cancel (A same mapping).
__global__ void pack_bfrag(const float* __restrict__ f_w, const float* __restrict__ i_w,
                           const float* __restrict__ u_w, const float* __restrict__ o_w,
                           uint4* __restrict__ bfragsG) {
    int idx = blockIdx.x * 256 + threadIdx.x;      // 0..32767
    int l = idx & 63, q = (idx >> 6) & 7, n = idx >> 9;
    int col = n * 16 + (l & 15);
    int g = col >> 8, j = col & 255;
    const float* W = (g == 0) ? f_w : (g == 1) ? i_w : (g == 2) ? u_w : o_w;
    union { uint4 u; _Float16 h[8]; } P;
#pragma unroll
    for (int e = 0; e < 8; ++e) {
        int k = q * 32 + ((l >> 4) * 8) + e;       // 0..255 (h part only)
        P.h[e] = (_Float16)W[j * 260 + 4 + k];
    }
    bfragsG[idx] = P.u;
}

// ---------------- prep: x-part weights xwG[g][k][j] f16 ----------------
__global__ void pack_xw(const float* __restrict__ f_w, const float* __restrict__ i_w,
                        const float* __restrict__ u_w, const float* __restrict__ o_w,
                        _Float16* __restrict__ xwG) {
    int t = blockIdx.x * 256 + threadIdx.x;        // 0..4095
    int g = t >> 10, k = (t >> 8) & 3, j = t & 255;
    const float* W = (g == 0) ? f_w : (g == 1) ? i_w : (g == 2) ? u_w : o_w;
    xwG[t] = (_Float16)W[j * 260 + k];
}

// ---------------- QCNN feature extractor ----------------
__global__ void qcnn_kernel(const float* __restrict__ in, const float* __restrict__ qw,
                            _Float16* __restrict__ feats) {
    int r = blockIdx.x * 256 + threadIdx.x;   // 0..131071
    const float* x = in + (size_t)r * 8;
    float v0[8];
#pragma unroll
    for (int i = 0; i < 8; ++i) v0[i] = x[i];
    float v1[16];
#pragma unroll
    for (int o = 0; o < 16; ++o) {
        float s = qw[128 + o];
#pragma unroll
        for (int i = 0; i < 8; ++i) s += qw[o*8 + i] * v0[i];
        v1[o] = tanhf_(s);
    }
    float v2[16];
#pragma unroll
    for (int o = 0; o < 16; ++o) {
        float s = qw[400 + o];
#pragma unroll
        for (int i = 0; i < 16; ++i) s += qw[144 + o*16 + i] * v1[i];
        v2[o] = tanhf_(s);
    }
    float v3[12];
#pragma unroll
    for (int o = 0; o < 12; ++o) {
        float s = qw[608 + o];
#pragma unroll
        for (int i = 0; i < 16; ++i) s += qw[416 + o*16 + i] * v2[i];
        v3[o] = tanhf_(s);
    }
    float v4[8];
#pragma unroll
    for (int o = 0; o < 8; ++o) {
        float s = qw[716 + o];
#pragma unroll
        for (int i = 0; i < 12; ++i) s += qw[620 + o*12 + i] * v3[i];
        v4[o] = tanhf_(s);
    }
    float v5[4];
#pragma unroll
    for (int o = 0; o < 4; ++o) {
        float s = qw[756 + o];
#pragma unroll
        for (int i = 0; i < 8; ++i) s += qw[724 + o*8 + i] * v4[i];
        v5[o] = tanhf_(s);
    }
    union { uint32_t u[2]; _Float16 h[4]; } P;
#pragma unroll
    for (int o = 0; o < 4; ++o) {
        float s = qw[776 + o];
#pragma unroll
        for (int i = 0; i < 4; ++i) s += qw[760 + o*4 + i] * v5[i];
        P.h[o] = (_Float16)tanhf_(s);
    }
    *reinterpret_cast<uint2*>(feats + (size_t)r * 4) = make_uint2(P.u[0], P.u[1]);
}

// ---------------- persistent MFMA LSTM: 256 blocks x 256 threads ----------------
// FINAL operating point (r10, 637us, absmax 9.77e-4). (256,1): arch 252 +
// AGPR 256 — both sub-files near-max and the budget CLOSES (no silent remat).
// q0..3 asm-pinned in AGPR; q4,q5 in LDS (+ q6 of gate-o tiles); q6(f/i/u)+q7
// streamed from L2 under >=20-MFMA cover. In-lane epilogue via C-reg sample
// parity + sel4 (no LDS gate round-trip). One barrier/step.
// Falsified alternatives (637-685us all): all-resident B (r11), 2 waves/SIMD
// at 2x occupancy (r15), deferred head (r16), spread epilogue (r14) ->
// the residue above the MFMA floor is the M=2-of-16 structure itself;
// larger M is bounded by BATCH/blocks and cross-block sync is dead (r8).
__global__ __launch_bounds__(256, 1)
void lstm_kernel(const uint4* __restrict__ bfragsG, const _Float16* __restrict__ xwG,
                 const _Float16* __restrict__ feats,
                 const float* __restrict__ f_b, const float* __restrict__ i_b,
                 const float* __restrict__ u_b, const float* __restrict__ o_b,
                 const float* __restrict__ head_w, const float* __restrict__ head_bp,
                 float* __restrict__ out) {
    __shared__ uint4     blds45[2][64][64];          // 131072 B : B q=4,5 all tiles
    __shared__ uint4     blds6o[16][64];             //  16384 B : B q=6, tiles 48..63
    __shared__ __align__(16) _Float16 comb[2][2][256]; //  2048 B : [buf][sample][k]
    __shared__ float     redL[2][4][2];              //     64 B : [buf][wave][sample]

    const int tid = threadIdx.x;
    const int w   = tid >> 6;          // wave 0..3
    const int l   = tid & 63;
    const int d_  = l >> 4;            // lane's d-slot (0..3)
    const int jl  = (w * 4 + d_) * 16 + (l & 15);   // lane's output dim j
    const int s0  = blockIdx.x * 2;

    // ---- init LDS ----
    for (int idx = tid; idx < 8192; idx += 256) {
        int n = idx >> 7, qq = (idx >> 6) & 1, ll = idx & 63;
        blds45[qq][n][ll] = bfragsG[(n * 8 + 4 + qq) * 64 + ll];
    }
    for (int idx = tid; idx < 1024; idx += 256) {
        int nn = idx >> 6, ll = idx & 63;
        blds6o[nn][ll] = bfragsG[((48 + nn) * 8 + 6) * 64 + ll];
    }
    reinterpret_cast<uint32_t*>(&comb[0][0][0])[tid] = 0u;   // h_0 = 0 (buf 0)

    // ---- resident B -> AGPR (exactly 256 regs), q = 0..3 x 16 tiles ----
    f16x8 Br[16][4];
#pragma unroll
    for (int m = 0; m < 16; ++m) {
        const int n = (m >> 2) * 16 + w * 4 + (m & 3);
#pragma unroll
        for (int q = 0; q < 4; ++q) {
            Br[m][q] = *reinterpret_cast<const f16x8*>(bfragsG + (n * 8 + q) * 64 + l);
            asm volatile("" : "+a"(Br[m][q]));
        }
    }

    // ---- per-lane epilogue constants (at jl) ----
    float bias_[4] = { f_b[jl], i_b[jl], u_b[jl], o_b[jl] };
    uint32_t xwp0[4], xwp1[4];
#pragma unroll
    for (int g = 0; g < 4; ++g) {
        union { uint32_t u; _Float16 h[2]; } P;
        P.h[0] = xwG[g*1024 +       jl]; P.h[1] = xwG[g*1024 + 256 + jl];
        xwp0[g] = P.u;
        P.h[0] = xwG[g*1024 + 512 + jl]; P.h[1] = xwG[g*1024 + 768 + jl];
        xwp1[g] = P.u;
    }
    const float hwj = head_w[jl];
    const float hb  = head_bp[0];
    uint2 xr0 = *reinterpret_cast<const uint2*>(feats + ((size_t)0 * BATCH + s0    ) * 4);
    uint2 xr1 = *reinterpret_cast<const uint2*>(feats + ((size_t)0 * BATCH + s0 + 1) * 4);

    __syncthreads();

    float cs0 = 0.f, cs1 = 0.f;        // c-state for (jl, sample 0/1)

#pragma unroll 1
    for (int t = 0; t < T_STEPS; ++t) {
        const int cur = t & 1;
        uint2 xn0 = xr0, xn1 = xr1;
        if (t + 1 < T_STEPS) {
            xn0 = *reinterpret_cast<const uint2*>(feats + ((size_t)(t+1) * BATCH + s0    ) * 4);
            xn1 = *reinterpret_cast<const uint2*>(feats + ((size_t)(t+1) * BATCH + s0 + 1) * 4);
        }

        // ---- A fragments (8 x ds_read_b128); row r = sample r&1 ----
        const _Float16* ab = &comb[cur][l & 1][(l >> 4) * 8];
        f16x8 A_[8];
#pragma unroll
        for (int q = 0; q < 8; ++q)
            A_[q] = *reinterpret_cast<const f16x8*>(ab + q * 32);

        float gv0[4], gv1[4];          // selected gate values (samples 0,1)

        // ---- 4 gate blocks, ascending q within each ----
#pragma unroll
        for (int g = 0; g < 4; ++g) {
            // stream loads for this block (consumed at q6/q7, >=20 MFMAs later)
            f16x8 s6[4], s7[4];
#pragma unroll
            for (int d = 0; d < 4; ++d) {
                const int n = g * 16 + w * 4 + d;
                if (g < 3) s6[d] = *reinterpret_cast<const f16x8*>(bfragsG + (n * 8 + 6) * 64 + l);
                else       s6[d] = *reinterpret_cast<const f16x8*>(&blds6o[w * 4 + d][l]);
                s7[d] = *reinterpret_cast<const f16x8*>(bfragsG + (n * 8 + 7) * 64 + l);
            }
            // LDS q4,q5
            f16x8 b4[4], b5[4];
#pragma unroll
            for (int d = 0; d < 4; ++d) {
                const int n = g * 16 + w * 4 + d;
                b4[d] = *reinterpret_cast<const f16x8*>(&blds45[0][n][l]);
                b5[d] = *reinterpret_cast<const f16x8*>(&blds45[1][n][l]);
            }

            f32x4 c0 = {0.f,0.f,0.f,0.f}, c1 = {0.f,0.f,0.f,0.f};
            f32x4 c2 = {0.f,0.f,0.f,0.f}, c3 = {0.f,0.f,0.f,0.f};
            asm volatile("s_nop 0" : "+v"(c0), "+v"(c1), "+v"(c2), "+v"(c3));

            // q0..3: AGPR-resident (asm)
#pragma unroll
            for (int q = 0; q < 4; ++q) {
                MFMA_AG(c0, A_[q], Br[4*g+0][q]); MFMA_AG(c1, A_[q], Br[4*g+1][q]);
                MFMA_AG(c2, A_[q], Br[4*g+2][q]); MFMA_AG(c3, A_[q], Br[4*g+3][q]);
            }
            // q4..7: intrinsic (compiler-managed waits & hazards)
            c0 = __builtin_amdgcn_mfma_f32_16x16x32_f16(A_[4], b4[0], c0, 0, 0, 0);
            c1 = __builtin_amdgcn_mfma_f32_16x16x32_f16(A_[4], b4[1], c1, 0, 0, 0);
            c2 = __builtin_amdgcn_mfma_f32_16x16x32_f16(A_[4], b4[2], c2, 0, 0, 0);
            c3 = __builtin_amdgcn_mfma_f32_16x16x32_f16(A_[4], b4[3], c3, 0, 0, 0);
            c0 = __builtin_amdgcn_mfma_f32_16x16x32_f16(A_[5], b5[0], c0, 0, 0, 0);
            c1 = __builtin_amdgcn_mfma_f32_16x16x32_f16(A_[5], b5[1], c1, 0, 0, 0);
            c2 = __builtin_amdgcn_mfma_f32_16x16x32_f16(A_[5], b5[2], c2, 0, 0, 0);
            c3 = __builtin_amdgcn_mfma_f32_16x16x32_f16(A_[5], b5[3], c3, 0, 0, 0);
            c0 = __builtin_amdgcn_mfma_f32_16x16x32_f16(A_[6], s6[0], c0, 0, 0, 0);
            c1 = __builtin_amdgcn_mfma_f32_16x16x32_f16(A_[6], s6[1], c1, 0, 0, 0);
            c2 = __builtin_amdgcn_mfma_f32_16x16x32_f16(A_[6], s6[2], c2, 0, 0, 0);
            c3 = __builtin_amdgcn_mfma_f32_16x16x32_f16(A_[6], s6[3], c3, 0, 0, 0);
            c0 = __builtin_amdgcn_mfma_f32_16x16x32_f16(A_[7], s7[0], c0, 0, 0, 0);
            c1 = __builtin_amdgcn_mfma_f32_16x16x32_f16(A_[7], s7[1], c1, 0, 0, 0);
            c2 = __builtin_amdgcn_mfma_f32_16x16x32_f16(A_[7], s7[2], c2, 0, 0, 0);
            c3 = __builtin_amdgcn_mfma_f32_16x16x32_f16(A_[7], s7[3], c3, 0, 0, 0);

            // in-lane select: lane's d-slot picks its tile; regs 0/1 = samples 0/1
            gv0[g] = sel4(d_, c0[0], c1[0], c2[0], c3[0]);
            gv1[g] = sel4(d_, c0[1], c1[1], c2[1], c3[1]);
        }

        // ---- epilogue: all in-register, lane owns (jl, s=0) and (jl, s=1) ----
        float pre0[4], pre1[4];
#pragma unroll
        for (int g = 0; g < 4; ++g) {
            pre0[g] = fdot2(xwp0[g], xr0.x, fdot2(xwp1[g], xr0.y, gv0[g] + bias_[g]));
            pre1[g] = fdot2(xwp0[g], xr1.x, fdot2(xwp1[g], xr1.y, gv1[g] + bias_[g]));
        }
        const float fg0 = sigmoidf_(pre0[0]), fg1 = sigmoidf_(pre1[0]);
        const float ig0 = sigmoidf_(pre0[1]), ig1 = sigmoidf_(pre1[1]);
        const float ug0 = tanhf_(pre0[2]),    ug1 = tanhf_(pre1[2]);
        const float og0 = sigmoidf_(pre0[3]), og1 = sigmoidf_(pre1[3]);
        cs0 = fg0 * cs0 + ig0 * ug0;
        cs1 = fg1 * cs1 + ig1 * ug1;
        const float h0 = og0 * tanhf_(cs0);
        const float h1 = og1 * tanhf_(cs1);

        comb[cur ^ 1][0][jl] = (_Float16)h0;
        comb[cur ^ 1][1][jl] = (_Float16)h1;

        // head partials: full-wave reduce (64 distinct j per wave)
        float p0 = h0 * hwj, p1 = h1 * hwj;
#pragma unroll
        for (int off = 32; off; off >>= 1) {
            p0 += __shfl_xor(p0, off);
            p1 += __shfl_xor(p1, off);
        }
        if (l == 0) { redL[cur][w][0] = p0; redL[cur][w][1] = p1; }

        xr0 = xn0; xr1 = xn1;
        __syncthreads();                       // one barrier per step

        if (tid < 2)
            out[(size_t)t * BATCH + s0 + tid] =
                (redL[cur][0][tid] + redL[cur][1][tid]) +
                (redL[cur][2][tid] + redL[cur][3][tid]) + hb;
    }
}

extern "C" void kernel_launch(void* const* d_in, const int* in_sizes, int n_in,
                              void* d_out, int out_size, void* d_ws, size_t ws_size,
                              hipStream_t stream) {
    const float* inputs = (const float*)d_in[0];
    const float* fm_w = (const float*)d_in[1];  const float* fm_b = (const float*)d_in[2];
    const float* c1_w = (const float*)d_in[3];  const float* c1_b = (const float*)d_in[4];
    const float* p1_w = (const float*)d_in[5];  const float* p1_b = (const float*)d_in[6];
    const float* c2_w = (const float*)d_in[7];  const float* c2_b = (const float*)d_in[8];
    const float* p2_w = (const float*)d_in[9];  const float* p2_b = (const float*)d_in[10];
    const float* c3_w = (const float*)d_in[11]; const float* c3_b = (const float*)d_in[12];
    const float* f_w  = (const float*)d_in[13]; const float* f_b  = (const float*)d_in[14];
    const float* i_w  = (const float*)d_in[15]; const float* i_b  = (const float*)d_in[16];
    const float* u_w  = (const float*)d_in[17]; const float* u_b  = (const float*)d_in[18];
    const float* o_w  = (const float*)d_in[19]; const float* o_b  = (const float*)d_in[20];
    const float* head_w = (const float*)d_in[21];
    const float* head_b = (const float*)d_in[22];

    // workspace layout (16B aligned)
    uint4*     bfragsG = (uint4*)d_ws;                                // 524288 B
    _Float16*  xwG     = (_Float16*)((char*)d_ws + 524288);           //   8192 B
    _Float16*  feats   = (_Float16*)((char*)d_ws + 532480);           // 1048576 B
    float*     qw      = (float*)((char*)d_ws + 1581056);             //   3120 B

    hipLaunchKernelGGL(concat_qw, dim3(1), dim3(256), 0, stream,
                       fm_w, fm_b, c1_w, c1_b, p1_w, p1_b, c2_w, c2_b,
                       p2_w, p2_b, c3_w, c3_b, qw);
    hipLaunchKernelGGL(pack_bfrag, dim3(128), dim3(256), 0, stream,
                       f_w, i_w, u_w, o_w, bfragsG);
    hipLaunchKernelGGL(pack_xw, dim3(16), dim3(256), 0, stream,
                       f_w, i_w, u_w, o_w, xwG);
    hipLaunchKernelGGL(qcnn_kernel, dim3(512), dim3(256), 0, stream,
                       inputs, qw, feats);
    hipLaunchKernelGGL(lstm_kernel, dim3(256), dim3(256), 0, stream,
                       bfragsG, xwG, feats,
                       f_b, i_b, u_b, o_b, head_w, head_b, (float*)d_out);
}